// Round 4
// baseline (6481.719 us; speedup 1.0000x reference)
//
#include <hip/hip_runtime.h>
#include <hip/hip_bf16.h>
#include <cstdint>

typedef __attribute__((ext_vector_type(8))) short short8;
typedef __attribute__((ext_vector_type(4))) float f32x4;
typedef unsigned short ushortT;

#define SEQ 200
#define NB  256

__device__ __forceinline__ float b2f(ushortT u){
    union { unsigned u; float f; } v; v.u = ((unsigned)u) << 16; return v.f;
}
__device__ __forceinline__ ushortT f2b(float f){
    union { float f; unsigned u; } v; v.f = f;
    unsigned r = v.u + 0x7FFFu + ((v.u >> 16) & 1u);
    return (ushortT)(r >> 16);
}
__device__ __forceinline__ float sigm(float x){ return 1.0f / (1.0f + __expf(-x)); }
__device__ __forceinline__ float tanh_fast(float x){
    float ax = fabsf(x);
    float t = __expf(-2.0f * ax);
    float r = (1.0f - t) / (1.0f + t);
    return copysignf(r, x);
}

// ---- f32 -> bf16 bulk convert (n multiple of 1024) ----
__global__ void k_cvt(const float* __restrict__ in, ushortT* __restrict__ out){
    size_t i = ((size_t)blockIdx.x*256 + threadIdx.x)*4;
    float4 v = *(const float4*)(in + i);
    ushortT o[4] = { f2b(v.x), f2b(v.y), f2b(v.z), f2b(v.w) };
    *(int2*)(out + i) = *(int2*)o;
}

// ---- swizzle a (K x ncols) f32 row-major matrix into bf16 MFMA B-fragment tiles ----
// tile T (16 cols), kstep q (32 k): lane l holds B[k = q*32+(l>>4)*8+j][n = T*16+(l&15)], j=0..7
__global__ void k_swizzle(const float* __restrict__ src, int ncols,
                          ushortT* __restrict__ dst, int tile0){
    int Tl = blockIdx.x, q = blockIdx.y, l = threadIdx.x;
    int n  = Tl*16 + (l & 15);
    int kb = q*32 + (l >> 4)*8;
    short8 v;
    #pragma unroll
    for (int j = 0; j < 8; ++j) ((ushortT*)&v)[j] = f2b(src[(size_t)(kb + j)*ncols + n]);
    *(short8*)(dst + ((size_t)(tile0 + Tl)*8 + q)*512 + (size_t)l*8) = v;
}

// ---- tft = 1 - tanh((t/180*selw+selb)^2), stored as scan A-fragments (bf16) ----
// TFT[(g*SEQ+t)*1024 + q*512 + l*8 + j] = tft[batch g*16+(l&15)][u = q*32+(l>>4)*8+j]
__global__ void k_tft(const float* __restrict__ sts, const float* __restrict__ selw,
                      const float* __restrict__ selb, ushortT* __restrict__ tft){
    int l = threadIdx.x, g = blockIdx.x / SEQ, t = blockIdx.x % SEQ;
    int lm = l & 15, lq = l >> 4;
    float tv = sts[(size_t)(g*16 + lm)*SEQ + t] * (1.0f/180.0f);
    size_t base = (size_t)(g*SEQ + t)*1024 + (size_t)l*8;
    #pragma unroll
    for (int q = 0; q < 2; ++q){
        short8 v;
        #pragma unroll
        for (int j = 0; j < 8; ++j){
            int u = q*32 + lq*8 + j;
            float a = tv * selw[u] + selb[u];
            ((ushortT*)&v)[j] = f2b(1.0f - tanh_fast(a*a));
        }
        *(short8*)(tft + base + (size_t)q*512) = v;
    }
}

// ---- generic C[rows x 256] = A[rows x 256] @ Bswz(16 tiles) + bias(f32), bf16 out ----
__global__ __launch_bounds__(512) void k_gemm256(const ushortT* A,
        const ushortT* __restrict__ Bswz, const float* __restrict__ bias, ushortT* out){
    __shared__ ushortT stage[16*256];
    int tid = threadIdx.x, w = tid >> 6, l = tid & 63, lm = l & 15, lq = l >> 4;
    size_t r0 = (size_t)blockIdx.x * 16;
    const f32x4 fz = {0.f,0.f,0.f,0.f};
    f32x4 acc[2] = {fz, fz};
    for (int q = 0; q < 8; ++q){
        short8 a = *(const short8*)(A + (r0 + lm)*256 + q*32 + lq*8);
        #pragma unroll
        for (int p = 0; p < 2; ++p){
            int T = 2*w + p;
            short8 b = *(const short8*)(Bswz + ((size_t)T*8 + q)*512 + (size_t)l*8);
            acc[p] = __builtin_amdgcn_mfma_f32_16x16x32_bf16(a, b, acc[p], 0, 0, 0);
        }
    }
    #pragma unroll
    for (int p = 0; p < 2; ++p){
        int n = (2*w + p)*16 + lm;
        float bs = bias[n];
        #pragma unroll
        for (int r = 0; r < 4; ++r)
            stage[(lq*4 + r)*256 + n] = f2b(acc[p][r] + bs);
    }
    __syncthreads();
    int row = tid >> 5, c8 = tid & 31;
    int4 v = *(const int4*)(stage + row*256 + c8*8);
    *(int4*)(out + (r0 + row)*256 + (size_t)c8*8) = v;
}

// ---- gates pre-act: xg = A@Uall + (Wall_b+Uall_b), written in scan per-lane order ----
__global__ __launch_bounds__(512) void k_gemmgates(const ushortT* __restrict__ A,
        const ushortT* __restrict__ Bswz, const float* __restrict__ bW,
        const float* __restrict__ bU, ushortT* __restrict__ out){
    int tid = threadIdx.x, w = tid >> 6, l = tid & 63, lm = l & 15, lq = l >> 4;
    int g = blockIdx.x / SEQ, t = blockIdx.x % SEQ;
    const f32x4 fz = {0.f,0.f,0.f,0.f};
    f32x4 acc[8] = {fz,fz,fz,fz,fz,fz,fz,fz};
    const ushortT* Arow = A + ((size_t)(g*16 + lm)*SEQ + t)*256;
    for (int q = 0; q < 8; ++q){
        short8 a = *(const short8*)(Arow + q*32 + lq*8);
        #pragma unroll
        for (int gq = 0; gq < 4; ++gq)
        #pragma unroll
        for (int p = 0; p < 2; ++p){
            int T = gq*16 + 2*w + p;
            short8 b = *(const short8*)(Bswz + ((size_t)T*8 + q)*512 + (size_t)l*8);
            acc[gq*2+p] = __builtin_amdgcn_mfma_f32_16x16x32_bf16(a, b, acc[gq*2+p], 0, 0, 0);
        }
    }
    short8 ch[4];
    #pragma unroll
    for (int gq = 0; gq < 4; ++gq)
    #pragma unroll
    for (int p = 0; p < 2; ++p){
        int n = gq*256 + w*32 + p*16 + lm;
        float bs = bW[n] + bU[n];
        #pragma unroll
        for (int r = 0; r < 4; ++r)
            ((ushortT*)&ch[p*2 + (gq>>1)])[(gq&1)*4 + r] = f2b(acc[gq*2+p][r] + bs);
    }
    size_t base = (size_t)(g*SEQ + t)*16384 + (size_t)(w*64 + l)*32;
    #pragma unroll
    for (int ci = 0; ci < 4; ++ci) *(short8*)(out + base + ci*8) = ch[ci];
}

// ---- persistent TLSTM scan: 16 WGs, one per 16-batch-row group, 200 steps ----
// gates use h_{t-1}@Wall ; decay uses c_{t-1}@Wd ; ts computed in-scan = tft@time_w + time_b
__global__ __launch_bounds__(512) void k_scan(const ushortT* __restrict__ xg,
        const ushortT* __restrict__ tftg, const ushortT* __restrict__ Wswz,
        const ushortT* __restrict__ twswz, const float* __restrict__ wdb_g,
        const float* __restrict__ timeb, ushortT* __restrict__ hs,
        float* __restrict__ maxh, int write_hs){
    __shared__ ushortT hbuf[2][16*264];   // h staging, stride 264 to break bank conflicts
    __shared__ ushortT cbuf[2][16*264];   // c staging (bf16-rounded) for c@Wd
    int tid = threadIdx.x, w = tid >> 6, l = tid & 63, lm = l & 15, lq = l >> 4;
    int g = blockIdx.x;
    float wdb[2], tb[2];
    short8 twf[2][2];
    #pragma unroll
    for (int p = 0; p < 2; ++p){
        wdb[p] = wdb_g[w*32 + p*16 + lm];
        tb[p]  = timeb[w*32 + p*16 + lm];
        #pragma unroll
        for (int q2 = 0; q2 < 2; ++q2)
            twf[p][q2] = *(const short8*)(twswz + ((size_t)(2*w+p)*8 + q2)*512 + (size_t)l*8);
    }
    float c[8], hm[8];
    #pragma unroll
    for (int i = 0; i < 8; ++i){ c[i] = 0.0f; hm[i] = -2.0f; }
    for (int i = tid; i < 16*264; i += 512){
        hbuf[0][i] = 0; hbuf[1][i] = 0; cbuf[0][i] = 0; cbuf[1][i] = 0;
    }
    __syncthreads();
    const ushortT* xg_g  = xg   + (size_t)g*SEQ*16384 + (size_t)(w*64 + l)*32;
    const ushortT* tft_g = tftg + (size_t)g*SEQ*1024  + (size_t)l*8;
    const f32x4 fz = {0.f,0.f,0.f,0.f};

    for (int t = 0; t < SEQ; ++t){
        int pb = t & 1, ab = 1 - pb;
        // per-step inputs
        short8 xv[4];
        #pragma unroll
        for (int ci = 0; ci < 4; ++ci)
            xv[ci] = *(const short8*)(xg_g + (size_t)t*16384 + ci*8);
        short8 at[2];
        #pragma unroll
        for (int q2 = 0; q2 < 2; ++q2)
            at[q2] = *(const short8*)(tft_g + (size_t)t*1024 + (size_t)q2*512);

        // ts = tft @ time_w  (K=64)
        f32x4 acc_ts[2] = {fz, fz};
        #pragma unroll
        for (int q2 = 0; q2 < 2; ++q2)
        #pragma unroll
        for (int p = 0; p < 2; ++p)
            acc_ts[p] = __builtin_amdgcn_mfma_f32_16x16x32_bf16(at[q2], twf[p][q2], acc_ts[p], 0, 0, 0);

        f32x4 acc[10];
        #pragma unroll
        for (int i = 0; i < 10; ++i) acc[i] = fz;
        for (int q = 0; q < 8; ++q){
            short8 a  = *(const short8*)(&hbuf[ab][lm*264 + q*32 + lq*8]);
            short8 ca = *(const short8*)(&cbuf[ab][lm*264 + q*32 + lq*8]);
            #pragma unroll
            for (int i = 0; i < 8; ++i){
                int T = (i>>1)*16 + 2*w + (i&1);
                short8 b = *(const short8*)(Wswz + ((size_t)T*8 + q)*512 + (size_t)l*8);
                acc[i] = __builtin_amdgcn_mfma_f32_16x16x32_bf16(a, b, acc[i], 0, 0, 0);
            }
            #pragma unroll
            for (int p = 0; p < 2; ++p){
                int T = 64 + 2*w + p;   // Wd tiles
                short8 b = *(const short8*)(Wswz + ((size_t)T*8 + q)*512 + (size_t)l*8);
                acc[8+p] = __builtin_amdgcn_mfma_f32_16x16x32_bf16(ca, b, acc[8+p], 0, 0, 0);
            }
        }
        #pragma unroll
        for (int p = 0; p < 2; ++p)
        #pragma unroll
        for (int r = 0; r < 4; ++r){
            float F   = acc[0+p][r] + b2f(((ushortT*)&xv[p*2+0])[r]);
            float I   = acc[2+p][r] + b2f(((ushortT*)&xv[p*2+0])[4+r]);
            float O   = acc[4+p][r] + b2f(((ushortT*)&xv[p*2+1])[r]);
            float CT  = acc[6+p][r] + b2f(((ushortT*)&xv[p*2+1])[4+r]);
            float cwd = acc[8+p][r] + wdb[p];
            float ts  = acc_ts[p][r] + tb[p];
            float cc  = c[p*4+r];
            float cs1 = tanh_fast(cwd);
            float cadj = cc - cs1 + cs1*ts;
            float cn  = sigm(F)*cadj + sigm(I)*sigm(CT);
            float h   = sigm(O)*tanh_fast(cn);
            c[p*4+r]  = cn;
            hm[p*4+r] = fmaxf(hm[p*4+r], h);
            int col = w*32 + p*16 + lm;
            hbuf[pb][(lq*4 + r)*264 + col] = f2b(h);
            cbuf[pb][(lq*4 + r)*264 + col] = f2b(cn);
        }
        __syncthreads();
        if (write_hs){
            int row = tid >> 5, c8 = tid & 31;
            int4 v = *(const int4*)(&hbuf[pb][row*264 + c8*8]);
            *(int4*)(hs + ((size_t)(g*16 + row)*SEQ + t)*256 + (size_t)c8*8) = v;
        }
    }
    #pragma unroll
    for (int p = 0; p < 2; ++p)
    #pragma unroll
    for (int r = 0; r < 4; ++r)
        maxh[(size_t)(g*16 + lq*4 + r)*256 + w*32 + p*16 + lm] = hm[p*4+r];
}

// ---- snapshot e_k = x[:,0,:] (bf16) ----
__global__ void k_ekcopy(const ushortT* __restrict__ x, ushortT* __restrict__ ek){
    int b = blockIdx.x, l = threadIdx.x;   // 64 threads, 4 ushorts each
    ((int2*)(ek + (size_t)b*256))[l] = ((const int2*)(x + (size_t)b*SEQ*256))[l];
}

// ---- e_k @ w1[0:256] + w1_b (f32 weights) ----
__global__ void k_ekw(const ushortT* __restrict__ ek, const float* __restrict__ w1w,
                      const float* __restrict__ w1b, float* __restrict__ ekw){
    int b = blockIdx.x, l = threadIdx.x;
    float acc = w1b[l];
    const ushortT* e = ek + (size_t)b*256;
    for (int d = 0; d < 256; ++d)
        acc += b2f(e[d]) * w1w[(size_t)d*64 + l];
    ekw[b*64 + l] = acc;
}

// ---- attention + aligned + gen_x, one wave per (b, s') ----
__global__ __launch_bounds__(512) void k_attn(const ushortT* __restrict__ ekbuf,
        const ushortT* __restrict__ whk, const float* __restrict__ ekw,
        const float* __restrict__ w1w, const float* __restrict__ w2w,
        const float* __restrict__ w2b, const float* __restrict__ nn,
        const float* __restrict__ pn, ushortT* __restrict__ genx){
    int w = threadIdx.x >> 6, l = threadIdx.x & 63;
    int wid = blockIdx.x*8 + w;
    int b = wid / SEQ, sp = wid % SEQ;
    const ushortT* ek = ekbuf + (size_t)b*256;
    const ushortT* wr = whk + ((size_t)b*SEQ + (sp > 0 ? sp-1 : 0))*256;
    size_t orow = ((size_t)b*SEQ + sp)*256;
    float a0, a1;
    if (sp == 0){ a0 = 1.0f; a1 = 0.0f; }
    else {
        float acc = ekw[b*64 + l];
        for (int d = 0; d < 256; ++d)
            acc += b2f(wr[d]) * w1w[(size_t)(256 + d)*64 + l];
        float u  = tanh_fast(acc);
        float p0 = u * w2w[l*2 + 0];
        float p1 = u * w2w[l*2 + 1];
        #pragma unroll
        for (int off = 32; off >= 1; off >>= 1){
            p0 += __shfl_xor(p0, off, 64);
            p1 += __shfl_xor(p1, off, 64);
        }
        float v0 = p0 + w2b[0], v1 = p1 + w2b[1];
        a0 = sigm(v0 - v1); a1 = 1.0f - a0;
    }
    #pragma unroll
    for (int i = 0; i < 4; ++i){
        int d = i*64 + l;
        float al = b2f(ek[d])*a0 + b2f(wr[d])*a1;
        float gv = al + nn[orow + d] - pn[orow + d];
        genx[orow + d] = f2b(gv);
    }
}

// ---- heads: out = maxh @ out_w + out_b (all f32) ----
__global__ void k_final(const float* __restrict__ mh1, const float* __restrict__ mh2,
                        const float* __restrict__ ow, const float* __restrict__ ob,
                        float* __restrict__ outp){
    int th = threadIdx.x;
    const float* mh = blockIdx.x ? mh2 : mh1;
    int b = th >> 1, cc = th & 1;
    float acc = ob[cc];
    for (int d = 0; d < 256; ++d)
        acc += mh[b*256 + d] * ow[d*2 + cc];
    outp[blockIdx.x*512 + th] = acc;
}

extern "C" void kernel_launch(void* const* d_in, const int* in_sizes, int n_in,
                              void* d_out, int out_size, void* d_ws, size_t ws_size,
                              hipStream_t stream) {
    const float* input_seqs = (const float*)d_in[0];
    const float* seq_time   = (const float*)d_in[3];
    const float* nn     = (const float*)d_in[6];
    const float* pn     = (const float*)d_in[7];
    const float* emb2_w = (const float*)d_in[9];
    const float* emb2_b = (const float*)d_in[10];
    const float* Wall_w = (const float*)d_in[11];
    const float* Wall_b = (const float*)d_in[12];
    const float* Uall_w = (const float*)d_in[13];
    const float* Uall_b = (const float*)d_in[14];
    const float* Wd_w   = (const float*)d_in[15];
    const float* Wd_b   = (const float*)d_in[16];
    const float* time_w = (const float*)d_in[17];
    const float* time_b = (const float*)d_in[18];
    const float* sel_w  = (const float*)d_in[19];
    const float* sel_b  = (const float*)d_in[20];
    const float* whk_w  = (const float*)d_in[21];
    const float* whk_b  = (const float*)d_in[22];
    const float* w1_w   = (const float*)d_in[23];
    const float* w1_b   = (const float*)d_in[24];
    const float* w2_w   = (const float*)d_in[25];
    const float* w2_b   = (const float*)d_in[26];
    const float* out_w  = (const float*)d_in[27];
    const float* out_b  = (const float*)d_in[28];

    const size_t NSZ = (size_t)in_sizes[6];   // B*SEQ*D noise element count

    char* wsb = (char*)d_ws;
    size_t off = 0;
    auto alloc = [&](size_t bytes){ void* p = wsb + off; off += (bytes + 255) & ~(size_t)255; return p; };
    ushortT* Wswz  = (ushortT*)alloc(80u*8*512*2);     // Wall tiles 0..63, Wd tiles 64..79
    ushortT* Uswz  = (ushortT*)alloc(64u*8*512*2);
    ushortT* Eswz  = (ushortT*)alloc(16u*8*512*2);
    ushortT* Hswz  = (ushortT*)alloc(16u*8*512*2);
    ushortT* TWswz = (ushortT*)alloc(16u*8*512*2);     // time_w (only q=0,1 slots used)
    ushortT* TFT   = (ushortT*)alloc((size_t)16*SEQ*1024*2);   // 6.6 MB
    ushortT* X     = (ushortT*)alloc((size_t)NB*SEQ*256*2);    // 26.2 MB (reused as GENX)
    ushortT* XG    = (ushortT*)alloc((size_t)16*SEQ*16384*2);  // 100 MB
    ushortT* HS    = (ushortT*)alloc((size_t)NB*SEQ*256*2);    // 26.2 MB (also input bf16 staging)
    ushortT* EK    = (ushortT*)alloc((size_t)NB*256*2);
    float*  MAXH1  = (float*)alloc((size_t)NB*256*4);
    float*  MAXH2  = (float*)alloc((size_t)NB*256*4);
    float*  EKW    = (float*)alloc((size_t)NB*64*4);

    float* outp = (float*)d_out;
    // outputs 2,3 are pass-throughs (predicted_noise, normal_noise), f32
    hipMemcpyAsync(outp + 1024,       pn, NSZ*4, hipMemcpyDeviceToDevice, stream);
    hipMemcpyAsync(outp + 1024 + NSZ, nn, NSZ*4, hipMemcpyDeviceToDevice, stream);

    k_swizzle<<<dim3(64,8), 64, 0, stream>>>(Wall_w, 1024, Wswz, 0);
    k_swizzle<<<dim3(16,8), 64, 0, stream>>>(Wd_w,    256, Wswz, 64);
    k_swizzle<<<dim3(64,8), 64, 0, stream>>>(Uall_w, 1024, Uswz, 0);
    k_swizzle<<<dim3(16,8), 64, 0, stream>>>(emb2_w,  256, Eswz, 0);
    k_swizzle<<<dim3(16,8), 64, 0, stream>>>(whk_w,   256, Hswz, 0);
    k_swizzle<<<dim3(16,2), 64, 0, stream>>>(time_w,  256, TWswz, 0);  // K=64 → q<2

    k_tft<<<3200, 64, 0, stream>>>(seq_time, sel_w, sel_b, TFT);
    k_cvt<<<12800, 256, 0, stream>>>(input_seqs, HS);          // f32 input → bf16 (staged in HS)
    k_gemm256<<<3200, 512, 0, stream>>>(HS, Eswz, emb2_b, X);
    k_ekcopy<<<256, 64, 0, stream>>>(X, EK);
    k_ekw<<<256, 64, 0, stream>>>(EK, w1_w, w1_b, EKW);
    k_gemmgates<<<3200, 512, 0, stream>>>(X, Uswz, Wall_b, Uall_b, XG);
    k_scan<<<16, 512, 0, stream>>>(XG, TFT, Wswz, TWswz, Wd_b, time_b, HS, MAXH1, 1);
    k_gemm256<<<3200, 512, 0, stream>>>(HS, Hswz, whk_b, HS);   // whk in-place (block-local rows)
    k_attn<<<6400, 512, 0, stream>>>(EK, HS, EKW, w1_w, w2_w, w2_b, nn, pn, X);  // genx → X region
    k_gemmgates<<<3200, 512, 0, stream>>>(X, Uswz, Wall_b, Uall_b, XG);
    k_scan<<<16, 512, 0, stream>>>(XG, TFT, Wswz, TWswz, Wd_b, time_b, HS, MAXH2, 0);
    k_final<<<2, 512, 0, stream>>>(MAXH1, MAXH2, out_w, out_b, outp);
}